// Round 1
// baseline (909.537 us; speedup 1.0000x reference)
//
#include <hip/hip_runtime.h>
#include <hip/hip_bf16.h>
#include <hip/hip_fp16.h>
#include <math.h>

// T=1024 time steps, S=512 sequences, D=32 features, K=64 states (= wave width)
#define TT 1024
#define SS 512
#define DD 32
#define KK 64

#define LOG2PI_F 1.8378770664093453f

// Workspace layout (d_ws):
//   [0, 64MB)        : p''[T,S,K] fp16 (max-shifted emission probs)
//   [+0, +32KB)      : float mpart[8192] (per-wave sums of max log-emissions)
//   [+32KB, +2KB)    : float seq_logd[S]
#define PBUF_BYTES ((size_t)TT * SS * KK * 2)
#define EM_WPB 4
#define EM_BLOCKS 2048
#define NWAVES (EM_BLOCKS * EM_WPB)   // 8192

typedef float v2f __attribute__((ext_vector_type(2)));

__device__ __forceinline__ v2f fma2(v2f a, v2f b, v2f c) {
#if __has_builtin(__builtin_elementwise_fma)
    return __builtin_elementwise_fma(a, b, c);
#else
    v2f r; r.x = fmaf(a.x, b.x, c.x); r.y = fmaf(a.y, b.y, c.y); return r;
#endif
}

// ---------------------------------------------------------------------------
// Emission: one wave per batch of 64 (t,s) items; lane = state k.
// p''[t,s,k] = exp(logp - max_k logp); mpart[wave] = sum of per-item maxes.
// __launch_bounds__(256, 4): min 4 waves/EU => 128-VGPR cap. The w2+m2
// working set is 64 VGPRs; the default occupancy heuristic was capping
// below that and spilling it into the item loop (~290us for a ~40us job).
__global__ __launch_bounds__(EM_WPB * 64, 4) void emission_kernel(
    const float* __restrict__ data,      // [T,S,D]
    const float* __restrict__ means,     // [K,D]
    const float* __restrict__ covars,    // [K,D]
    __half* __restrict__ pbuf,           // [T,S,K]
    float* __restrict__ mpart)           // [NWAVES]
{
    const int k  = threadIdx.x & 63;
    const int wv = blockIdx.x * EM_WPB + (threadIdx.x >> 6);

    v2f w2[DD / 2], m2[DD / 2];
    float c0 = DD * LOG2PI_F;
#pragma unroll
    for (int d = 0; d < DD; ++d) {
        float c = covars[k * DD + d];
        ((float*)w2)[d] = 1.0f / c;
        ((float*)m2)[d] = means[k * DD + d];
        c0 += __logf(c);
    }

    const int ipw = (TT * SS) / NWAVES;  // 64
    const int base = wv * ipw;
    float macc = 0.0f;

#pragma unroll 2
    for (int i = 0; i < ipw; ++i) {
        const int item = base + i;                     // = t*S + s
        const float4* xp = (const float4*)(data + (size_t)item * DD);
        v2f q0 = {0.0f, 0.0f}, q1 = {0.0f, 0.0f};
#pragma unroll
        for (int d4 = 0; d4 < DD / 4; ++d4) {
            float4 x = xp[d4];
            v2f xa; xa.x = x.x; xa.y = x.y;
            v2f xb; xb.x = x.z; xb.y = x.w;
            v2f ta = xa - m2[2 * d4];
            v2f tb = xb - m2[2 * d4 + 1];
            q0 = fma2(w2[2 * d4] * ta, ta, q0);
            q1 = fma2(w2[2 * d4 + 1] * tb, tb, q1);
        }
        float q = (q0.x + q0.y) + (q1.x + q1.y);
        float logp = -0.5f * (q + c0);
        float mx = logp;
#pragma unroll
        for (int off = 32; off > 0; off >>= 1)
            mx = fmaxf(mx, __shfl_xor(mx, off, 64));
        pbuf[(size_t)item * KK + k] = __float2half(__expf(logp - mx));
        macc += mx;   // wave-uniform
    }
    if (k == 0) mpart[wv] = macc;
}

// ---------------------------------------------------------------------------
// Sequential forward recursion. One wave per QQ=2 sequences; lane = state.
// Single-wave block => NO s_barrier needed: LDS ops from one wave execute
// in order; wave_barrier() is a zero-cost compiler scheduling fence. This
// keeps the 8-deep emission-prob prefetch in flight.
//
// __launch_bounds__(64, 1): min 1 wave/EU => up to 512 VGPRs. The previous
// build reported VGPR_Count=56 (< the 64 VGPRs of acl alone) => the A-matrix
// columns were spilled into the 1024-step loop, putting a scratch reload on
// the serial dependency chain every step (732 cy/step measured vs ~300 true).
//
// 2-way sequence interleave: two independent recursions share the A columns
// and fill each other's LDS-roundtrip / shuffle stall cycles. Occupancy does
// not matter for this kernel (256 waves on 1024 SIMDs; wall time = per-wave
// chain latency), only chain length and issue slots do.
//
// Normalize (wave-reduce + log) only every 4th step: max-shifted emissions
// keep per-step den'' >= ~1e-5, so 4 raw steps stay >= ~1e-20 >> fp32 min.
#define QQ 2
__global__ __launch_bounds__(64, 1) void hmm_seq(
    const __half* __restrict__ pbuf,     // [T,S,K]
    const float* __restrict__ initial,   // [K]
    const float* __restrict__ trans,     // [K,K]
    float* __restrict__ out_alpha,       // [S,K]
    float* __restrict__ seq_logd)        // [S]
{
    const int k  = threadIdx.x;
    const int s0 = blockIdx.x * QQ;

    v2f acl[KK / 2];                     // pairs (A[2j][k], A[2j+1][k]) - shared by both seqs
#pragma unroll
    for (int j = 0; j < KK / 2; ++j) {
        acl[j].x = trans[(2 * j) * KK + k];
        acl[j].y = trans[(2 * j + 1) * KK + k];
    }

    __shared__ __align__(16) float ash[QQ][KK];

    const size_t PST = (size_t)SS * KK;  // elements per time step
    const __half* pp = pbuf + (size_t)s0 * KK + k;

    __half pf[QQ][8];                    // 8-deep prefetch ring per sequence
#pragma unroll
    for (int i = 0; i < 8; ++i)
#pragma unroll
        for (int q = 0; q < QQ; ++q)
            pf[q][i] = pp[PST * (size_t)i + q * KK];

    const float init_k = initial[k];
    float logd[QQ], av[QQ];
#pragma unroll
    for (int q = 0; q < QQ; ++q) { logd[q] = 0.0f; av[q] = 0.0f; }

    for (int mblk = 0; mblk < TT / 8; ++mblk) {
#pragma unroll
        for (int i = 0; i < 8; ++i) {
            const int t = 8 * mblk + i;
            int tn = t + 8; if (tn >= TT) tn = TT - 1;   // clamped (uniform)
#pragma unroll
            for (int q = 0; q < QQ; ++q) {
                const float pc = __half2float(pf[q][i]);
                pf[q][i] = pp[PST * (size_t)tn + q * KK];

                float a;
                if (mblk == 0 && i == 0) {
                    a = init_k * pc;
                } else {
                    const float4* ash4 = (const float4*)ash[q];
                    v2f a0 = {0,0}, a1 = {0,0}, a2 = {0,0}, a3 = {0,0};
#pragma unroll
                    for (int j4 = 0; j4 < KK / 4; ++j4) {
                        float4 avv = ash4[j4];
                        v2f lo; lo.x = avv.x; lo.y = avv.y;
                        v2f hi; hi.x = avv.z; hi.y = avv.w;
                        if (j4 & 1) {
                            a2 = fma2(lo, acl[2 * j4], a2);
                            a3 = fma2(hi, acl[2 * j4 + 1], a3);
                        } else {
                            a0 = fma2(lo, acl[2 * j4], a0);
                            a1 = fma2(hi, acl[2 * j4 + 1], a1);
                        }
                    }
                    v2f sv = (a0 + a1) + (a2 + a3);
                    a = pc * (sv.x + sv.y);
                }

                if ((t & 3) == 3) {      // i==3 or i==7: compile-time folded
                    float den = a;
#pragma unroll
                    for (int off = 32; off > 0; off >>= 1)
                        den += __shfl_xor(den, off, 64);
                    logd[q] += __logf(den);
                    a *= __builtin_amdgcn_rcpf(den);
                }

                av[q] = a;
                ash[q][k] = a;
            }
            __builtin_amdgcn_wave_barrier();   // order LDS writes vs next reads
        }
    }

#pragma unroll
    for (int q = 0; q < QQ; ++q) {
        out_alpha[(size_t)(s0 + q) * KK + k] = av[q];  // t=1023 ends normalized
        if (k == 0) seq_logd[s0 + q] = logd[q];
    }
}

// ---------------------------------------------------------------------------
// nll = -( sum_s seq_logd[s] + sum_w mpart[w] )
__global__ __launch_bounds__(256) void finalize(
    const float* __restrict__ seq_logd, const float* __restrict__ mpart,
    float* __restrict__ out_nll)
{
    float v = 0.0f;
    for (int j = threadIdx.x; j < NWAVES; j += 256) v += mpart[j];
    for (int j = threadIdx.x; j < SS; j += 256) v += seq_logd[j];
#pragma unroll
    for (int off = 32; off > 0; off >>= 1)
        v += __shfl_xor(v, off, 64);
    __shared__ float sh[4];
    if ((threadIdx.x & 63) == 0) sh[threadIdx.x >> 6] = v;
    __syncthreads();
    if (threadIdx.x == 0) {
        double total = ((double)sh[0] + sh[1]) + ((double)sh[2] + sh[3]);
        out_nll[0] = (float)(-total);
    }
}

extern "C" void kernel_launch(void* const* d_in, const int* in_sizes, int n_in,
                              void* d_out, int out_size, void* d_ws, size_t ws_size,
                              hipStream_t stream) {
    const float* data    = (const float*)d_in[0];  // [T,S,D]
    const float* initial = (const float*)d_in[1];  // [K]
    const float* trans   = (const float*)d_in[2];  // [K,K]
    const float* means   = (const float*)d_in[3];  // [K,D]
    const float* covars  = (const float*)d_in[4];  // [K,D]

    float* out_alpha = (float*)d_out;                    // [S,K]
    float* out_nll   = (float*)d_out + (size_t)SS * KK;  // 1 float

    __half* pbuf     = (__half*)d_ws;
    float*  mpart    = (float*)((char*)d_ws + PBUF_BYTES);
    float*  seq_logd = (float*)((char*)d_ws + PBUF_BYTES + NWAVES * sizeof(float));

    emission_kernel<<<EM_BLOCKS, EM_WPB * 64, 0, stream>>>(
        data, means, covars, pbuf, mpart);
    hmm_seq<<<SS / QQ, 64, 0, stream>>>(pbuf, initial, trans, out_alpha, seq_logd);
    finalize<<<1, 256, 0, stream>>>(seq_logd, mpart, out_nll);
}

// Round 2
// 516.179 us; speedup vs baseline: 1.7621x; 1.7621x over previous
//
#include <hip/hip_runtime.h>
#include <hip/hip_bf16.h>
#include <hip/hip_fp16.h>
#include <math.h>

// T=1024 time steps, S=512 sequences, D=32 features, K=64 states (= wave width)
#define TT 1024
#define SS 512
#define DD 32
#define KK 64

#define LOG2PI_F 1.8378770664093453f

// Workspace layout (d_ws):
//   [0, 64MB)        : p''[T,S,K] fp16 (max-shifted emission probs)
//   [+0, +32KB)      : float mpart[8192] (per-wave sums of max log-emissions)
//   [+32KB, +2KB)    : float seq_logd[S]
#define PBUF_BYTES ((size_t)TT * SS * KK * 2)
#define EM_WPB 4
#define EM_BLOCKS 2048
#define NWAVES (EM_BLOCKS * EM_WPB)   // 8192

typedef float v2f __attribute__((ext_vector_type(2)));

__device__ __forceinline__ v2f fma2(v2f a, v2f b, v2f c) {
#if __has_builtin(__builtin_elementwise_fma)
    return __builtin_elementwise_fma(a, b, c);
#else
    v2f r; r.x = fmaf(a.x, b.x, c.x); r.y = fmaf(a.y, b.y, c.y); return r;
#endif
}

// ---------------------------------------------------------------------------
// DPP wave64 reductions: 6 VALU-latency ops (~50 cy serial) instead of a
// 6-deep ds_bpermute (__shfl_xor) chain (~600-700 cy serial DS latency).
// Sum/max lands in lane 63; broadcast via readlane -> SGPR.
// DPP ctrl: row_shr:n = 0x110+n, row_bcast:15 = 0x142, row_bcast:31 = 0x143.
template <int CTRL, int RMASK>
__device__ __forceinline__ float dpp_add(float x) {
    // old=0, bound_ctrl=1: out-of-bounds / masked rows contribute 0.
    int t = __builtin_amdgcn_update_dpp(0, __float_as_int(x), CTRL, RMASK, 0xf, true);
    return x + __int_as_float(t);
}
template <int CTRL, int RMASK>
__device__ __forceinline__ float dpp_max(float x) {
    // old=x, bound_ctrl=0: out-of-bounds / masked rows yield x (max identity).
    int xi = __float_as_int(x);
    int t = __builtin_amdgcn_update_dpp(xi, xi, CTRL, RMASK, 0xf, false);
    return fmaxf(x, __int_as_float(t));
}

__device__ __forceinline__ float wave_reduce_sum(float x) {
    x = dpp_add<0x111, 0xf>(x);   // row_shr:1
    x = dpp_add<0x112, 0xf>(x);   // row_shr:2
    x = dpp_add<0x114, 0xf>(x);   // row_shr:4
    x = dpp_add<0x118, 0xf>(x);   // row_shr:8  -> lane15/31/47/63 hold row sums
    x = dpp_add<0x142, 0xa>(x);   // row_bcast:15 into rows 1,3
    x = dpp_add<0x143, 0xc>(x);   // row_bcast:31 into rows 2,3 -> lane63 total
    return __int_as_float(__builtin_amdgcn_readlane(__float_as_int(x), 63));
}
__device__ __forceinline__ float wave_reduce_max(float x) {
    x = dpp_max<0x111, 0xf>(x);
    x = dpp_max<0x112, 0xf>(x);
    x = dpp_max<0x114, 0xf>(x);
    x = dpp_max<0x118, 0xf>(x);
    x = dpp_max<0x142, 0xa>(x);
    x = dpp_max<0x143, 0xc>(x);
    return __int_as_float(__builtin_amdgcn_readlane(__float_as_int(x), 63));
}

// ---------------------------------------------------------------------------
// Emission: one wave per batch of 64 (t,s) items; lane = state k.
// p''[t,s,k] = exp(logp - max_k logp); mpart[wave] = sum of per-item maxes.
// amdgpu_waves_per_eu(2,4): VGPR budget 256 (w2+m2 working set is 64 VGPRs;
// the default occupancy heuristic capped below that and spilled it into the
// item loop — ~290us for a ~25us-of-HBM job, unchanged by __launch_bounds__).
__global__ __launch_bounds__(EM_WPB * 64)
__attribute__((amdgpu_waves_per_eu(2, 4)))
void emission_kernel(
    const float* __restrict__ data,      // [T,S,D]
    const float* __restrict__ means,     // [K,D]
    const float* __restrict__ covars,    // [K,D]
    __half* __restrict__ pbuf,           // [T,S,K]
    float* __restrict__ mpart)           // [NWAVES]
{
    const int k  = threadIdx.x & 63;
    const int wv = blockIdx.x * EM_WPB + (threadIdx.x >> 6);

    v2f w2[DD / 2], m2[DD / 2];
    float c0 = DD * LOG2PI_F;
#pragma unroll
    for (int d = 0; d < DD; ++d) {
        float c = covars[k * DD + d];
        ((float*)w2)[d] = 1.0f / c;
        ((float*)m2)[d] = means[k * DD + d];
        c0 += __logf(c);
    }

    const int ipw = (TT * SS) / NWAVES;  // 64
    const int base = wv * ipw;
    float macc = 0.0f;

#pragma unroll 2
    for (int i = 0; i < ipw; ++i) {
        const int item = base + i;                     // = t*S + s
        const float4* xp = (const float4*)(data + (size_t)item * DD);
        v2f q0 = {0.0f, 0.0f}, q1 = {0.0f, 0.0f};
#pragma unroll
        for (int d4 = 0; d4 < DD / 4; ++d4) {
            float4 x = xp[d4];
            v2f xa; xa.x = x.x; xa.y = x.y;
            v2f xb; xb.x = x.z; xb.y = x.w;
            v2f ta = xa - m2[2 * d4];
            v2f tb = xb - m2[2 * d4 + 1];
            q0 = fma2(w2[2 * d4] * ta, ta, q0);
            q1 = fma2(w2[2 * d4 + 1] * tb, tb, q1);
        }
        float q = (q0.x + q0.y) + (q1.x + q1.y);
        float logp = -0.5f * (q + c0);
        float mx = wave_reduce_max(logp);              // DPP, ~50 cy serial
        pbuf[(size_t)item * KK + k] = __float2half(__expf(logp - mx));
        macc += mx;   // wave-uniform
    }
    if (k == 0) mpart[wv] = macc;
}

// ---------------------------------------------------------------------------
// Sequential forward recursion. One wave per sequence; lane = state.
// Single-wave block => NO s_barrier needed: LDS ops from one wave execute
// in order; wave_barrier() is a zero-cost compiler scheduling fence.
//
// amdgpu_waves_per_eu(1,1): VGPR budget 512. Rounds 0-1 allocated only
// 56/64 VGPRs (acl alone needs 64) => the A-matrix columns were spilled
// into the 1024-step serial loop (732 cy/step measured vs ~300 true chain);
// __launch_bounds__(64,1) did NOT raise the budget. Runtime occupancy is
// truly <=1 wave/EU (512 waves on 1024 SIMDs), so (1,1) costs nothing.
//
// Normalize (DPP reduce + log) only every 4th step: max-shifted emissions
// keep per-step den'' >= ~1e-5, so 4 raw steps stay >= ~1e-20 >> fp32 min.
__global__ __launch_bounds__(64)
__attribute__((amdgpu_waves_per_eu(1, 1)))
void hmm_seq(
    const __half* __restrict__ pbuf,     // [T,S,K]
    const float* __restrict__ initial,   // [K]
    const float* __restrict__ trans,     // [K,K]
    float* __restrict__ out_alpha,       // [S,K]
    float* __restrict__ seq_logd)        // [S]
{
    const int s = blockIdx.x;
    const int k = threadIdx.x;

    v2f acl[KK / 2];                     // pairs (A[2j][k], A[2j+1][k])
#pragma unroll
    for (int j = 0; j < KK / 2; ++j) {
        acl[j].x = trans[(2 * j) * KK + k];
        acl[j].y = trans[(2 * j + 1) * KK + k];
    }

    __shared__ __align__(16) float alpha_sh[KK];

    const __half* pp = pbuf + (size_t)s * KK + k;
    const size_t PST = (size_t)SS * KK;  // elements per time step

    __half pf[8];                        // 8-deep prefetch ring
#pragma unroll
    for (int i = 0; i < 8; ++i) pf[i] = pp[PST * i];

    const float init_k = initial[k];
    float logd = 0.0f;
    float a = 0.0f;

    for (int mblk = 0; mblk < TT / 8; ++mblk) {
#pragma unroll
        for (int i = 0; i < 8; ++i) {
            const int t = 8 * mblk + i;
            const float pc = __half2float(pf[i]);
            int tn = t + 8; if (tn >= TT) tn = TT - 1;   // clamped (uniform)
            pf[i] = pp[PST * (size_t)tn];

            if (mblk == 0 && i == 0) {
                a = init_k * pc;
            } else {
                const float4* ash4 = (const float4*)alpha_sh;
                v2f a0 = {0,0}, a1 = {0,0}, a2 = {0,0}, a3 = {0,0};
#pragma unroll
                for (int j4 = 0; j4 < KK / 4; ++j4) {
                    float4 av = ash4[j4];
                    v2f lo; lo.x = av.x; lo.y = av.y;
                    v2f hi; hi.x = av.z; hi.y = av.w;
                    if (j4 & 1) {
                        a2 = fma2(lo, acl[2 * j4], a2);
                        a3 = fma2(hi, acl[2 * j4 + 1], a3);
                    } else {
                        a0 = fma2(lo, acl[2 * j4], a0);
                        a1 = fma2(hi, acl[2 * j4 + 1], a1);
                    }
                }
                v2f sv = (a0 + a1) + (a2 + a3);
                a = pc * (sv.x + sv.y);
            }

            if ((t & 3) == 3) {
                float den = wave_reduce_sum(a);        // DPP, ~50 cy serial
                logd += __logf(den);
                a *= __builtin_amdgcn_rcpf(den);
            }

            alpha_sh[k] = a;
            __builtin_amdgcn_wave_barrier();   // order LDS write vs next reads
        }
    }

    out_alpha[(size_t)s * KK + k] = a;   // t=1023 ends on a normalize step
    if (k == 0) seq_logd[s] = logd;
}

// ---------------------------------------------------------------------------
// nll = -( sum_s seq_logd[s] + sum_w mpart[w] )
__global__ __launch_bounds__(256) void finalize(
    const float* __restrict__ seq_logd, const float* __restrict__ mpart,
    float* __restrict__ out_nll)
{
    float v = 0.0f;
    for (int j = threadIdx.x; j < NWAVES; j += 256) v += mpart[j];
    for (int j = threadIdx.x; j < SS; j += 256) v += seq_logd[j];
#pragma unroll
    for (int off = 32; off > 0; off >>= 1)
        v += __shfl_xor(v, off, 64);
    __shared__ float sh[4];
    if ((threadIdx.x & 63) == 0) sh[threadIdx.x >> 6] = v;
    __syncthreads();
    if (threadIdx.x == 0) {
        double total = ((double)sh[0] + sh[1]) + ((double)sh[2] + sh[3]);
        out_nll[0] = (float)(-total);
    }
}

extern "C" void kernel_launch(void* const* d_in, const int* in_sizes, int n_in,
                              void* d_out, int out_size, void* d_ws, size_t ws_size,
                              hipStream_t stream) {
    const float* data    = (const float*)d_in[0];  // [T,S,D]
    const float* initial = (const float*)d_in[1];  // [K]
    const float* trans   = (const float*)d_in[2];  // [K,K]
    const float* means   = (const float*)d_in[3];  // [K,D]
    const float* covars  = (const float*)d_in[4];  // [K,D]

    float* out_alpha = (float*)d_out;                    // [S,K]
    float* out_nll   = (float*)d_out + (size_t)SS * KK;  // 1 float

    __half* pbuf     = (__half*)d_ws;
    float*  mpart    = (float*)((char*)d_ws + PBUF_BYTES);
    float*  seq_logd = (float*)((char*)d_ws + PBUF_BYTES + NWAVES * sizeof(float));

    emission_kernel<<<EM_BLOCKS, EM_WPB * 64, 0, stream>>>(
        data, means, covars, pbuf, mpart);
    hmm_seq<<<SS, 64, 0, stream>>>(pbuf, initial, trans, out_alpha, seq_logd);
    finalize<<<1, 256, 0, stream>>>(seq_logd, mpart, out_nll);
}

// Round 3
// 355.109 us; speedup vs baseline: 2.5613x; 1.4536x over previous
//
#include <hip/hip_runtime.h>
#include <hip/hip_bf16.h>
#include <hip/hip_fp16.h>
#include <math.h>

// T=1024 time steps, S=512 sequences, D=32 features, K=64 states (= wave width)
#define TT 1024
#define SS 512
#define DD 32
#define KK 64

#define LOG2PI_F 1.8378770664093453f

// Segmented forward recursion: seg0 covers t in [0,512); seg1 burns in from
// t=448 (flat init, contraction kills the init error) and emits [512,1024).
#define NSEG 2
#define SPLIT 512
#define BURN 64

// Workspace layout (d_ws):
//   [0, 64MB)            : p''[T,S,K] fp16 (max-shifted emission probs)
//   [+0, +32KB)          : float mpart[8192] (per-wave sums of max log-emissions)
//   [+32KB, +4KB)        : float seq_logd[NSEG*S]
//   [+36KB, +18KB)       : float tables[K*72]  (w[32], mw[32], c0', pad)
#define PBUF_BYTES ((size_t)TT * SS * KK * 2)
#define EM_WPB 4
#define EM_BLOCKS 2048
#define NWAVES (EM_BLOCKS * EM_WPB)   // 8192 waves, 64 items each = T*S

typedef float v2f __attribute__((ext_vector_type(2)));

__device__ __forceinline__ v2f fma2(v2f a, v2f b, v2f c) {
#if __has_builtin(__builtin_elementwise_fma)
    return __builtin_elementwise_fma(a, b, c);
#else
    v2f r; r.x = fmaf(a.x, b.x, c.x); r.y = fmaf(a.y, b.y, c.y); return r;
#endif
}

// ---------------------------------------------------------------------------
// DPP wave64 sum reduction: 6 VALU-latency ops; result broadcast via readlane.
template <int CTRL, int RMASK>
__device__ __forceinline__ float dpp_add(float x) {
    int t = __builtin_amdgcn_update_dpp(0, __float_as_int(x), CTRL, RMASK, 0xf, true);
    return x + __int_as_float(t);
}
__device__ __forceinline__ float wave_reduce_sum(float x) {
    x = dpp_add<0x111, 0xf>(x);   // row_shr:1
    x = dpp_add<0x112, 0xf>(x);   // row_shr:2
    x = dpp_add<0x114, 0xf>(x);   // row_shr:4
    x = dpp_add<0x118, 0xf>(x);   // row_shr:8  -> lane15/31/47/63 hold row sums
    x = dpp_add<0x142, 0xa>(x);   // row_bcast:15 into rows 1,3
    x = dpp_add<0x143, 0xc>(x);   // row_bcast:31 into rows 2,3 -> lane63 total
    return __int_as_float(__builtin_amdgcn_readlane(__float_as_int(x), 63));
}

// ---------------------------------------------------------------------------
// Prep: per-state constant tables so the emission inner loop uses only
// wave-uniform (scalar) operands.  tables[k*72 + 0..31] = 1/covar,
// [32..63] = mean/covar, [64] = sum(log covar) + sum(mean^2/covar) + D*log2pi.
__global__ __launch_bounds__(64) void prep_kernel(
    const float* __restrict__ means, const float* __restrict__ covars,
    float* __restrict__ tables)
{
    const int k = threadIdx.x;
    float c0 = DD * LOG2PI_F;
    for (int d = 0; d < DD; ++d) {
        float c = covars[k * DD + d];
        float m = means[k * DD + d];
        float w = 1.0f / c;
        float mw = m * w;
        tables[k * 72 + d] = w;
        tables[k * 72 + 32 + d] = mw;
        c0 += __logf(c) + m * mw;
    }
    tables[k * 72 + 64] = c0;
}

// ---------------------------------------------------------------------------
// Emission, transposed: lane = item (t,s), loop over states k.
//  - item data loaded ONCE per lane, coalesced (2 x dwordx4) -> registers.
//  - per-state tables are wave-uniform -> scalar loads (SMEM pipe), no
//    per-item broadcast VMEM (round-2's 512 broadcast loads/wave were the
//    ~225us bottleneck: serialized L2 latency).
//  - max over k is per-lane (no cross-lane op per item).
//  - 128B store per item is contiguous.
// logp[64] fully unrolled => static indexing (runtime-indexed arrays spill
// to scratch). q = x^2*w - 2*x*mw + c0'  ==  (x-m)^2*w + log-terms.
__global__ __launch_bounds__(EM_WPB * 64)
__attribute__((amdgpu_waves_per_eu(2, 8)))
void emission_kernel(
    const float* __restrict__ data,      // [T,S,D]
    const float* __restrict__ tables,    // [K,72]
    __half* __restrict__ pbuf,           // [T,S,K]
    float* __restrict__ mpart)           // [NWAVES]
{
    const int lane = threadIdx.x & 63;
    const int wv = blockIdx.x * EM_WPB + (threadIdx.x >> 6);
    const int item = wv * 64 + lane;     // = t*S + s

    const float4* xp = (const float4*)(data + (size_t)item * DD);
    v2f xv[DD / 2], x2v[DD / 2];
#pragma unroll
    for (int d4 = 0; d4 < DD / 4; ++d4) {
        float4 x = xp[d4];
        v2f a; a.x = x.x; a.y = x.y;
        v2f b; b.x = x.z; b.y = x.w;
        xv[2 * d4] = a;       xv[2 * d4 + 1] = b;
        x2v[2 * d4] = a * a;  x2v[2 * d4 + 1] = b * b;
    }

    float logp[KK];
    float mx = -3.4e38f;
#pragma unroll
    for (int k = 0; k < KK; ++k) {
        const float* tb = tables + k * 72;          // uniform -> s_load
        const v2f* w2  = (const v2f*)tb;
        const v2f* mw2 = (const v2f*)(tb + 32);
        v2f qa0 = {0,0}, qa1 = {0,0}, qb0 = {0,0}, qb1 = {0,0};
#pragma unroll
        for (int j = 0; j < DD / 4; ++j) {
            qa0 = fma2(x2v[2 * j],     w2[2 * j],      qa0);
            qa1 = fma2(x2v[2 * j + 1], w2[2 * j + 1],  qa1);
            qb0 = fma2(xv[2 * j],      mw2[2 * j],     qb0);
            qb1 = fma2(xv[2 * j + 1],  mw2[2 * j + 1], qb1);
        }
        v2f qa = qa0 + qa1, qb = qb0 + qb1;
        float q = (qa.x + qa.y) - 2.0f * (qb.x + qb.y) + tb[64];
        float lp = -0.5f * q;
        logp[k] = lp;
        mx = fmaxf(mx, lp);
    }

    unsigned int out[KK / 2];
#pragma unroll
    for (int k = 0; k < KK; k += 2) {
        float e0 = __expf(logp[k] - mx);
        float e1 = __expf(logp[k + 1] - mx);
        __half2 h = __halves2half2(__float2half(e0), __float2half(e1));
        out[k / 2] = *(unsigned int*)&h;
    }
    float4* op = (float4*)(pbuf + (size_t)item * KK);
#pragma unroll
    for (int j = 0; j < KK / 8; ++j) op[j] = ((float4*)out)[j];

    float msum = wave_reduce_sum(mx);    // sum of the wave's 64 item-maxes
    if (lane == 0) mpart[wv] = msum;
}

// ---------------------------------------------------------------------------
// Sequential forward recursion, segmented. One wave per (sequence, segment);
// lane = state. blockIdx.y = segment:
//   seg0: t in [0, 512), emits logd from t=0, init = initial[k]*p0.
//   seg1: t in [448, 1024): 64 burn-in steps from flat init (normalized but
//         logd NOT accumulated; contraction of the normalized recursion kills
//         the init error by ~lambda^64), then emits logd for t >= 512 and the
//         final alpha. Serial depth 1024 -> 576; waves 512 -> 1024 (all SIMDs).
// amdgpu_waves_per_eu(1,1): VGPR budget 512 so acl[] (64 VGPRs) stays
// register-resident (132 VGPRs total, no spill - fixed in round 2).
// Normalize (DPP reduce + log) only every 4th step; t0 % 8 == 0 for both
// segments so the (t&3)==3 test folds at compile time in the unrolled body.
__global__ __launch_bounds__(64)
__attribute__((amdgpu_waves_per_eu(1, 1)))
void hmm_seq(
    const __half* __restrict__ pbuf,     // [T,S,K]
    const float* __restrict__ initial,   // [K]
    const float* __restrict__ trans,     // [K,K]
    float* __restrict__ out_alpha,       // [S,K]
    float* __restrict__ seq_logd)        // [NSEG*S]
{
    const int s   = blockIdx.x;
    const int seg = blockIdx.y;
    const int k   = threadIdx.x;

    const int t0        = seg ? (SPLIT - BURN) : 0;       // 448 / 0
    const int nsteps    = seg ? (TT - SPLIT + BURN) : SPLIT;  // 576 / 512
    const int emit_from = seg ? SPLIT : 0;

    v2f acl[KK / 2];                     // pairs (A[2j][k], A[2j+1][k])
#pragma unroll
    for (int j = 0; j < KK / 2; ++j) {
        acl[j].x = trans[(2 * j) * KK + k];
        acl[j].y = trans[(2 * j + 1) * KK + k];
    }

    __shared__ __align__(16) float alpha_sh[KK];

    const __half* pp = pbuf + (size_t)s * KK + k;
    const size_t PST = (size_t)SS * KK;  // elements per time step

    __half pf[8];                        // 8-deep prefetch ring
#pragma unroll
    for (int i = 0; i < 8; ++i) pf[i] = pp[PST * (size_t)(t0 + i)];

    const float init_k = seg ? 1.0f : initial[k];
    float logd = 0.0f;
    float a = 0.0f;

    for (int mblk = 0; mblk < nsteps / 8; ++mblk) {
#pragma unroll
        for (int i = 0; i < 8; ++i) {
            const int t = t0 + 8 * mblk + i;
            const float pc = __half2float(pf[i]);
            int tn = t + 8; if (tn >= TT) tn = TT - 1;   // clamped (uniform)
            pf[i] = pp[PST * (size_t)tn];

            if (mblk == 0 && i == 0) {
                a = init_k * pc;
            } else {
                const float4* ash4 = (const float4*)alpha_sh;
                v2f a0 = {0,0}, a1 = {0,0}, a2 = {0,0}, a3 = {0,0};
#pragma unroll
                for (int j4 = 0; j4 < KK / 4; ++j4) {
                    float4 av = ash4[j4];
                    v2f lo; lo.x = av.x; lo.y = av.y;
                    v2f hi; hi.x = av.z; hi.y = av.w;
                    if (j4 & 1) {
                        a2 = fma2(lo, acl[2 * j4], a2);
                        a3 = fma2(hi, acl[2 * j4 + 1], a3);
                    } else {
                        a0 = fma2(lo, acl[2 * j4], a0);
                        a1 = fma2(hi, acl[2 * j4 + 1], a1);
                    }
                }
                v2f sv = (a0 + a1) + (a2 + a3);
                a = pc * (sv.x + sv.y);
            }

            if ((t & 3) == 3) {          // i==3 or i==7 (t0 % 8 == 0)
                float den = wave_reduce_sum(a);        // DPP, ~50 cy serial
                logd += (t >= emit_from) ? __logf(den) : 0.0f;
                a *= __builtin_amdgcn_rcpf(den);
            }

            alpha_sh[k] = a;
            __builtin_amdgcn_wave_barrier();   // order LDS write vs next reads
        }
    }

    if (seg) out_alpha[(size_t)s * KK + k] = a;   // t=1023 ends normalized
    if (k == 0) seq_logd[seg * SS + s] = logd;
}

// ---------------------------------------------------------------------------
// nll = -( sum seq_logd + sum mpart )
__global__ __launch_bounds__(256) void finalize(
    const float* __restrict__ seq_logd, const float* __restrict__ mpart,
    float* __restrict__ out_nll)
{
    float v = 0.0f;
    for (int j = threadIdx.x; j < NWAVES; j += 256) v += mpart[j];
    for (int j = threadIdx.x; j < NSEG * SS; j += 256) v += seq_logd[j];
#pragma unroll
    for (int off = 32; off > 0; off >>= 1)
        v += __shfl_xor(v, off, 64);
    __shared__ float sh[4];
    if ((threadIdx.x & 63) == 0) sh[threadIdx.x >> 6] = v;
    __syncthreads();
    if (threadIdx.x == 0) {
        double total = ((double)sh[0] + sh[1]) + ((double)sh[2] + sh[3]);
        out_nll[0] = (float)(-total);
    }
}

extern "C" void kernel_launch(void* const* d_in, const int* in_sizes, int n_in,
                              void* d_out, int out_size, void* d_ws, size_t ws_size,
                              hipStream_t stream) {
    const float* data    = (const float*)d_in[0];  // [T,S,D]
    const float* initial = (const float*)d_in[1];  // [K]
    const float* trans   = (const float*)d_in[2];  // [K,K]
    const float* means   = (const float*)d_in[3];  // [K,D]
    const float* covars  = (const float*)d_in[4];  // [K,D]

    float* out_alpha = (float*)d_out;                    // [S,K]
    float* out_nll   = (float*)d_out + (size_t)SS * KK;  // 1 float

    __half* pbuf     = (__half*)d_ws;
    float*  mpart    = (float*)((char*)d_ws + PBUF_BYTES);
    float*  seq_logd = (float*)((char*)d_ws + PBUF_BYTES + NWAVES * sizeof(float));
    float*  tables   = (float*)((char*)d_ws + PBUF_BYTES + NWAVES * sizeof(float)
                                + NSEG * SS * sizeof(float));

    prep_kernel<<<1, 64, 0, stream>>>(means, covars, tables);
    emission_kernel<<<EM_BLOCKS, EM_WPB * 64, 0, stream>>>(
        data, tables, pbuf, mpart);
    hmm_seq<<<dim3(SS, NSEG), 64, 0, stream>>>(
        pbuf, initial, trans, out_alpha, seq_logd);
    finalize<<<1, 256, 0, stream>>>(seq_logd, mpart, out_nll);
}

// Round 4
// 345.903 us; speedup vs baseline: 2.6295x; 1.0266x over previous
//
#include <hip/hip_runtime.h>
#include <hip/hip_bf16.h>
#include <hip/hip_fp16.h>
#include <math.h>

// T=1024 time steps, S=512 sequences, D=32 features, K=64 states (= wave width)
#define TT 1024
#define SS 512
#define DD 32
#define KK 64

#define LOG2PI_F 1.8378770664093453f

// Segmented forward recursion: NSEG segments of TT/NSEG emitted steps each;
// seg>0 burns in BURN steps from a flat init (contraction of the normalized
// recursion kills the init error; round-3 measured it below f16 noise).
#define NSEG 4
#define SEGLEN (TT / NSEG)   // 256
#define BURN 64

// Workspace layout (d_ws):
//   [0, 64MB)            : p''[T,S,K] fp16 (max-shifted emission probs)
//   [+0, +32KB)          : float mpart[8192] (per-wave sums of max log-emissions)
//   [+32KB, +8KB)        : float seq_logd[NSEG*S]
#define PBUF_BYTES ((size_t)TT * SS * KK * 2)
#define EM_WPB 4
#define EM_BLOCKS 2048
#define NWAVES (EM_BLOCKS * EM_WPB)   // 8192 waves, 64 items each = T*S

typedef float v2f __attribute__((ext_vector_type(2)));

__device__ __forceinline__ v2f fma2(v2f a, v2f b, v2f c) {
#if __has_builtin(__builtin_elementwise_fma)
    return __builtin_elementwise_fma(a, b, c);
#else
    v2f r; r.x = fmaf(a.x, b.x, c.x); r.y = fmaf(a.y, b.y, c.y); return r;
#endif
}

// ---------------------------------------------------------------------------
// DPP wave64 reductions: 6 VALU-latency ops (~50 cy serial) instead of a
// 6-deep ds_bpermute (__shfl_xor) chain (~600 cy serial DS latency).
// Result lands in lane 63; broadcast via readlane -> SGPR.
template <int CTRL, int RMASK>
__device__ __forceinline__ float dpp_add(float x) {
    int t = __builtin_amdgcn_update_dpp(0, __float_as_int(x), CTRL, RMASK, 0xf, true);
    return x + __int_as_float(t);
}
template <int CTRL, int RMASK>
__device__ __forceinline__ float dpp_max(float x) {
    int xi = __float_as_int(x);
    int t = __builtin_amdgcn_update_dpp(xi, xi, CTRL, RMASK, 0xf, false);
    return fmaxf(x, __int_as_float(t));
}
__device__ __forceinline__ float wave_reduce_sum(float x) {
    x = dpp_add<0x111, 0xf>(x);   // row_shr:1
    x = dpp_add<0x112, 0xf>(x);   // row_shr:2
    x = dpp_add<0x114, 0xf>(x);   // row_shr:4
    x = dpp_add<0x118, 0xf>(x);   // row_shr:8
    x = dpp_add<0x142, 0xa>(x);   // row_bcast:15 into rows 1,3
    x = dpp_add<0x143, 0xc>(x);   // row_bcast:31 into rows 2,3 -> lane63 total
    return __int_as_float(__builtin_amdgcn_readlane(__float_as_int(x), 63));
}
__device__ __forceinline__ float wave_reduce_max(float x) {
    x = dpp_max<0x111, 0xf>(x);
    x = dpp_max<0x112, 0xf>(x);
    x = dpp_max<0x114, 0xf>(x);
    x = dpp_max<0x118, 0xf>(x);
    x = dpp_max<0x142, 0xa>(x);
    x = dpp_max<0x143, 0xc>(x);
    return __int_as_float(__builtin_amdgcn_readlane(__float_as_int(x), 63));
}

// ---------------------------------------------------------------------------
// Emission: one wave per batch of 64 (t,s) items; lane = state k (round-0
// structure: per-lane constants in VGPRs, item data broadcast to all lanes).
// Round-3's lane=item + "uniform s_load tables" variant stayed ~160us: the
// table operands (64 states x 65 floats) cannot live in SGPRs, so they became
// per-iteration VMEM broadcast loads (serialized L2 latency). Here the only
// broadcast VMEM is the item data, explicitly double-buffered one item ahead
// so its latency hides under the ~170-cycle per-item compute; the max
// reduction is DPP (round-2 win) instead of a 6-deep shuffle chain.
__device__ __forceinline__ float em_process(
    const float4* __restrict__ x8, const v2f* __restrict__ w2,
    const v2f* __restrict__ m2, float c0, int item, int k,
    __half* __restrict__ pbuf)
{
    v2f q0 = {0.0f, 0.0f}, q1 = {0.0f, 0.0f};
#pragma unroll
    for (int d4 = 0; d4 < DD / 4; ++d4) {
        float4 x = x8[d4];
        v2f xa; xa.x = x.x; xa.y = x.y;
        v2f xb; xb.x = x.z; xb.y = x.w;
        v2f ta = xa - m2[2 * d4];
        v2f tb = xb - m2[2 * d4 + 1];
        q0 = fma2(w2[2 * d4] * ta, ta, q0);
        q1 = fma2(w2[2 * d4 + 1] * tb, tb, q1);
    }
    float q = (q0.x + q0.y) + (q1.x + q1.y);
    float logp = -0.5f * (q + c0);
    float mx = wave_reduce_max(logp);            // DPP, wave-uniform result
    pbuf[(size_t)item * KK + k] = __float2half(__expf(logp - mx));
    return mx;
}

__global__ __launch_bounds__(EM_WPB * 64)
__attribute__((amdgpu_waves_per_eu(2, 8)))
void emission_kernel(
    const float* __restrict__ data,      // [T,S,D]
    const float* __restrict__ means,     // [K,D]
    const float* __restrict__ covars,    // [K,D]
    __half* __restrict__ pbuf,           // [T,S,K]
    float* __restrict__ mpart)           // [NWAVES]
{
    const int k  = threadIdx.x & 63;
    const int wv = blockIdx.x * EM_WPB + (threadIdx.x >> 6);

    v2f w2[DD / 2], m2[DD / 2];
    float c0 = DD * LOG2PI_F;
#pragma unroll
    for (int d = 0; d < DD; ++d) {
        float c = covars[k * DD + d];
        ((float*)w2)[d] = 1.0f / c;
        ((float*)m2)[d] = means[k * DD + d];
        c0 += __logf(c);
    }

    const int base = wv * 64;            // 64 consecutive items per wave
    float macc = 0.0f;

    float4 xa8[DD / 4], xb8[DD / 4];     // double-buffered item prefetch
    {
        const float4* xp = (const float4*)(data + (size_t)base * DD);
#pragma unroll
        for (int j = 0; j < DD / 4; ++j) xa8[j] = xp[j];
    }

    for (int i = 0; i < 64; i += 2) {
        {   // prefetch item i+1 while computing item i
            const float4* xp = (const float4*)(data + (size_t)(base + i + 1) * DD);
#pragma unroll
            for (int j = 0; j < DD / 4; ++j) xb8[j] = xp[j];
        }
        macc += em_process(xa8, w2, m2, c0, base + i, k, pbuf);
        if (i + 2 < 64) {   // guard: last wave must not read past data end
            const float4* xp = (const float4*)(data + (size_t)(base + i + 2) * DD);
#pragma unroll
            for (int j = 0; j < DD / 4; ++j) xa8[j] = xp[j];
        }
        macc += em_process(xb8, w2, m2, c0, base + i + 1, k, pbuf);
    }
    if (k == 0) mpart[wv] = macc;        // macc is wave-uniform
}

// ---------------------------------------------------------------------------
// Sequential forward recursion, segmented. One wave per (sequence, segment);
// lane = state. blockIdx.y = segment:
//   seg0:   t in [0, 256), emits logd from t=0, init = initial[k]*p0.
//   seg>0:  t in [seg*256-64, (seg+1)*256): 64 burn-in steps from flat init
//           (normalized, logd NOT accumulated), then emits its 256 steps.
// Serial depth 576 -> 320; waves 1024 -> 2048 (2 per SIMD: per-wave VALUBusy
// is only ~27%, so two segment-waves overlap each other's LDS-latency stalls).
// amdgpu_waves_per_eu(1,2): min=1 keeps the 512-VGPR budget (acl[] stays
// register-resident at 132 VGPRs; the round-2 fix), max=2 for co-residency.
// Normalize (DPP reduce + log) only every 4th step; t0 % 8 == 0 for all
// segments so the (t&3)==3 test folds at compile time in the unrolled body.
__global__ __launch_bounds__(64)
__attribute__((amdgpu_waves_per_eu(1, 2)))
void hmm_seq(
    const __half* __restrict__ pbuf,     // [T,S,K]
    const float* __restrict__ initial,   // [K]
    const float* __restrict__ trans,     // [K,K]
    float* __restrict__ out_alpha,       // [S,K]
    float* __restrict__ seq_logd)        // [NSEG*S]
{
    const int s   = blockIdx.x;
    const int seg = blockIdx.y;
    const int k   = threadIdx.x;

    const int emit_from = seg * SEGLEN;
    const int t0        = seg ? (emit_from - BURN) : 0;
    const int nsteps    = seg ? (SEGLEN + BURN) : SEGLEN;

    v2f acl[KK / 2];                     // pairs (A[2j][k], A[2j+1][k])
#pragma unroll
    for (int j = 0; j < KK / 2; ++j) {
        acl[j].x = trans[(2 * j) * KK + k];
        acl[j].y = trans[(2 * j + 1) * KK + k];
    }

    __shared__ __align__(16) float alpha_sh[KK];

    const __half* pp = pbuf + (size_t)s * KK + k;
    const size_t PST = (size_t)SS * KK;  // elements per time step

    __half pf[8];                        // 8-deep prefetch ring
#pragma unroll
    for (int i = 0; i < 8; ++i) pf[i] = pp[PST * (size_t)(t0 + i)];

    const float init_k = seg ? 1.0f : initial[k];
    float logd = 0.0f;
    float a = 0.0f;

    for (int mblk = 0; mblk < nsteps / 8; ++mblk) {
#pragma unroll
        for (int i = 0; i < 8; ++i) {
            const int t = t0 + 8 * mblk + i;
            const float pc = __half2float(pf[i]);
            int tn = t + 8; if (tn >= TT) tn = TT - 1;   // clamped (uniform)
            pf[i] = pp[PST * (size_t)tn];

            if (mblk == 0 && i == 0) {
                a = init_k * pc;
            } else {
                const float4* ash4 = (const float4*)alpha_sh;
                v2f a0 = {0,0}, a1 = {0,0}, a2 = {0,0}, a3 = {0,0};
#pragma unroll
                for (int j4 = 0; j4 < KK / 4; ++j4) {
                    float4 av = ash4[j4];
                    v2f lo; lo.x = av.x; lo.y = av.y;
                    v2f hi; hi.x = av.z; hi.y = av.w;
                    if (j4 & 1) {
                        a2 = fma2(lo, acl[2 * j4], a2);
                        a3 = fma2(hi, acl[2 * j4 + 1], a3);
                    } else {
                        a0 = fma2(lo, acl[2 * j4], a0);
                        a1 = fma2(hi, acl[2 * j4 + 1], a1);
                    }
                }
                v2f sv = (a0 + a1) + (a2 + a3);
                a = pc * (sv.x + sv.y);
            }

            if ((t & 3) == 3) {          // i==3 or i==7 (t0 % 8 == 0)
                float den = wave_reduce_sum(a);        // DPP, ~50 cy serial
                logd += (t >= emit_from) ? __logf(den) : 0.0f;
                a *= __builtin_amdgcn_rcpf(den);
            }

            alpha_sh[k] = a;
            __builtin_amdgcn_wave_barrier();   // order LDS write vs next reads
        }
    }

    if (seg == NSEG - 1) out_alpha[(size_t)s * KK + k] = a;  // t=1023 normalized
    if (k == 0) seq_logd[seg * SS + s] = logd;
}

// ---------------------------------------------------------------------------
// nll = -( sum seq_logd + sum mpart )
__global__ __launch_bounds__(256) void finalize(
    const float* __restrict__ seq_logd, const float* __restrict__ mpart,
    float* __restrict__ out_nll)
{
    float v = 0.0f;
    for (int j = threadIdx.x; j < NWAVES; j += 256) v += mpart[j];
    for (int j = threadIdx.x; j < NSEG * SS; j += 256) v += seq_logd[j];
#pragma unroll
    for (int off = 32; off > 0; off >>= 1)
        v += __shfl_xor(v, off, 64);
    __shared__ float sh[4];
    if ((threadIdx.x & 63) == 0) sh[threadIdx.x >> 6] = v;
    __syncthreads();
    if (threadIdx.x == 0) {
        double total = ((double)sh[0] + sh[1]) + ((double)sh[2] + sh[3]);
        out_nll[0] = (float)(-total);
    }
}

extern "C" void kernel_launch(void* const* d_in, const int* in_sizes, int n_in,
                              void* d_out, int out_size, void* d_ws, size_t ws_size,
                              hipStream_t stream) {
    const float* data    = (const float*)d_in[0];  // [T,S,D]
    const float* initial = (const float*)d_in[1];  // [K]
    const float* trans   = (const float*)d_in[2];  // [K,K]
    const float* means   = (const float*)d_in[3];  // [K,D]
    const float* covars  = (const float*)d_in[4];  // [K,D]

    float* out_alpha = (float*)d_out;                    // [S,K]
    float* out_nll   = (float*)d_out + (size_t)SS * KK;  // 1 float

    __half* pbuf     = (__half*)d_ws;
    float*  mpart    = (float*)((char*)d_ws + PBUF_BYTES);
    float*  seq_logd = (float*)((char*)d_ws + PBUF_BYTES + NWAVES * sizeof(float));

    emission_kernel<<<EM_BLOCKS, EM_WPB * 64, 0, stream>>>(
        data, means, covars, pbuf, mpart);
    hmm_seq<<<dim3(SS, NSEG), 64, 0, stream>>>(
        pbuf, initial, trans, out_alpha, seq_logd);
    finalize<<<1, 256, 0, stream>>>(seq_logd, mpart, out_nll);
}

// Round 5
// 302.320 us; speedup vs baseline: 3.0085x; 1.1442x over previous
//
#include <hip/hip_runtime.h>
#include <hip/hip_fp16.h>
#include <math.h>

// T=1024 time steps, S=512 sequences, D=32 features, K=64 states (= wave width)
#define TT 1024
#define SS 512
#define DD 32
#define KK 64

#define LOG2PI_F 1.8378770664093453f

// Segmented forward recursion: NSEG segments of TT/NSEG emitted steps each;
// seg>0 burns in BURN steps from a flat init (contraction of the normalized
// recursion kills the init error; rounds 3-4 measured it below noise).
#define NSEG 4
#define SEGLEN (TT / NSEG)   // 256
#define BURN 64

// Workspace layout (d_ws): float seq_logd[NSEG*S] only (pbuf/mpart deleted —
// emission is fused into the recursion, saving 128 MB of HBM round-trip).

typedef float v2f __attribute__((ext_vector_type(2)));

__device__ __forceinline__ v2f fma2(v2f a, v2f b, v2f c) {
#if __has_builtin(__builtin_elementwise_fma)
    return __builtin_elementwise_fma(a, b, c);
#else
    v2f r; r.x = fmaf(a.x, b.x, c.x); r.y = fmaf(a.y, b.y, c.y); return r;
#endif
}

// ---------------------------------------------------------------------------
// DPP wave64 reductions: 6 VALU-latency ops (~50 cy serial) instead of a
// 6-deep ds_bpermute (__shfl_xor) chain. Result broadcast via readlane.
template <int CTRL, int RMASK>
__device__ __forceinline__ float dpp_add(float x) {
    int t = __builtin_amdgcn_update_dpp(0, __float_as_int(x), CTRL, RMASK, 0xf, true);
    return x + __int_as_float(t);
}
template <int CTRL, int RMASK>
__device__ __forceinline__ float dpp_max(float x) {
    int xi = __float_as_int(x);
    int t = __builtin_amdgcn_update_dpp(xi, xi, CTRL, RMASK, 0xf, false);
    return fmaxf(x, __int_as_float(t));
}
__device__ __forceinline__ float wave_reduce_sum(float x) {
    x = dpp_add<0x111, 0xf>(x);   // row_shr:1
    x = dpp_add<0x112, 0xf>(x);   // row_shr:2
    x = dpp_add<0x114, 0xf>(x);   // row_shr:4
    x = dpp_add<0x118, 0xf>(x);   // row_shr:8
    x = dpp_add<0x142, 0xa>(x);   // row_bcast:15 into rows 1,3
    x = dpp_add<0x143, 0xc>(x);   // row_bcast:31 into rows 2,3 -> lane63 total
    return __int_as_float(__builtin_amdgcn_readlane(__float_as_int(x), 63));
}
__device__ __forceinline__ float wave_reduce_max(float x) {
    x = dpp_max<0x111, 0xf>(x);
    x = dpp_max<0x112, 0xf>(x);
    x = dpp_max<0x114, 0xf>(x);
    x = dpp_max<0x118, 0xf>(x);
    x = dpp_max<0x142, 0xa>(x);
    x = dpp_max<0x143, 0xc>(x);
    return __int_as_float(__builtin_amdgcn_readlane(__float_as_int(x), 63));
}

// ---------------------------------------------------------------------------
// Fused emission + forward recursion. One wave per (sequence, segment);
// lane = state k. Emission for step t is computed IN-WAVE from data[t,s,:]:
//   - x[t,s,:] (128 B, wave-uniform) is double-buffered one full step
//     (~700 cy) ahead -> load latency trivially covered.
//   - the 48 pk-FMA quad-form + DPP max + exp depend only on data, not on
//     alpha, so they fill the recursion chain's stall windows (round-3/4
//     measured the chain at ~700 cy/step with only ~30% VALU issue).
//   - p stays in f32 (beats the old f16 pbuf) and 128 MB of pbuf HBM
//     round-trip plus the entire ~164 us emission dispatch disappear.
// Max-shift bookkeeping: p'' = exp(logp - mx_t); each wave accumulates
// sum(mx_t) over its EMITTED steps (each (t,s) counted exactly once across
// segments) into seq_logd together with sum(log den'').
// amdgpu_waves_per_eu(2,2): 256-VGPR cap (acl 64 + w/m 64 + x-ring 64 +
// temps ~= 225 fits) so the (SS x NSEG)=2048-wave grid runs 2 waves/SIMD.
// Normalize (DPP reduce + log) only every 4th step; t0 % 8 == 0 for all
// segments so the (t&3)==3 test folds at compile time in the unrolled body.
__global__ __launch_bounds__(64)
__attribute__((amdgpu_waves_per_eu(2, 2)))
void hmm_fused(
    const float* __restrict__ data,      // [T,S,D]
    const float* __restrict__ initial,   // [K]
    const float* __restrict__ trans,     // [K,K]
    const float* __restrict__ means,     // [K,D]
    const float* __restrict__ covars,    // [K,D]
    float* __restrict__ out_alpha,       // [S,K]
    float* __restrict__ seq_logd)        // [NSEG*S]
{
    const int s   = blockIdx.x;
    const int seg = blockIdx.y;
    const int k   = threadIdx.x;

    const int emit_from = seg * SEGLEN;
    const int t0        = seg ? (emit_from - BURN) : 0;
    const int nsteps    = seg ? (SEGLEN + BURN) : SEGLEN;

    // Per-lane (state-k) emission constants: 1/covar, mean, c0 = D*log2pi
    // + sum(log covar). Coalesced loads (lane-consecutive within each d).
    v2f w2[DD / 2], m2[DD / 2];
    float c0 = DD * LOG2PI_F;
#pragma unroll
    for (int d = 0; d < DD; ++d) {
        float c = covars[k * DD + d];
        ((float*)w2)[d] = 1.0f / c;
        ((float*)m2)[d] = means[k * DD + d];
        c0 += __logf(c);
    }

    v2f acl[KK / 2];                     // pairs (A[2j][k], A[2j+1][k])
#pragma unroll
    for (int j = 0; j < KK / 2; ++j) {
        acl[j].x = trans[(2 * j) * KK + k];
        acl[j].y = trans[(2 * j + 1) * KK + k];
    }

    __shared__ __align__(16) float alpha_sh[KK];

    // x double-buffer: wave-uniform broadcast loads (8 x dwordx4 = 128 B),
    // named arrays + compile-time selection (runtime-indexed arrays spill).
    float4 xA[DD / 4], xB[DD / 4];
    {
        const float4* xp = (const float4*)(data + ((size_t)t0 * SS + s) * DD);
#pragma unroll
        for (int j = 0; j < DD / 4; ++j) xA[j] = xp[j];
    }

    const float init_k = seg ? 1.0f : initial[k];
    float logd = 0.0f;                   // sum(log den'') over emitted steps
    float macc = 0.0f;                   // sum(mx) over emitted steps
    float a = 0.0f;

    // One fused step: prefetch x(t+1) into XNXT, emission from XCUR,
    // recursion step, conditional normalize, LDS publish.
#define FUSED_STEP(XCUR, XNXT, Ii)                                            \
    {                                                                         \
        const int t = t0 + 8 * mblk + (Ii);                                   \
        int tn = t + 1; if (tn >= TT) tn = TT - 1;       /* uniform clamp */  \
        const float4* xp =                                                    \
            (const float4*)(data + ((size_t)tn * SS + s) * DD);               \
        _Pragma("unroll")                                                     \
        for (int j = 0; j < DD / 4; ++j) XNXT[j] = xp[j];                     \
        /* emission: q_k = sum_d w[k,d]*(x_d - m[k,d])^2  (off-chain) */      \
        v2f q0 = {0.0f, 0.0f}, q1 = {0.0f, 0.0f};                             \
        _Pragma("unroll")                                                     \
        for (int d4 = 0; d4 < DD / 4; ++d4) {                                 \
            float4 x = XCUR[d4];                                              \
            v2f xa; xa.x = x.x; xa.y = x.y;                                   \
            v2f xb; xb.x = x.z; xb.y = x.w;                                   \
            v2f ta = xa - m2[2 * d4];                                         \
            v2f tb = xb - m2[2 * d4 + 1];                                     \
            q0 = fma2(w2[2 * d4] * ta, ta, q0);                               \
            q1 = fma2(w2[2 * d4 + 1] * tb, tb, q1);                           \
        }                                                                     \
        float qq = (q0.x + q0.y) + (q1.x + q1.y);                             \
        float logp = -0.5f * (qq + c0);                                       \
        float mx = wave_reduce_max(logp);        /* DPP, wave-uniform */      \
        float pc = __expf(logp - mx);                                         \
        if (t >= emit_from) macc += mx;                                       \
        /* recursion: a = pc * (alpha . A[:,k]) */                            \
        if ((Ii) == 0 && mblk == 0) {                                         \
            a = init_k * pc;                                                  \
        } else {                                                              \
            const float4* ash4 = (const float4*)alpha_sh;                     \
            v2f a0 = {0,0}, a1 = {0,0}, a2 = {0,0}, a3 = {0,0};               \
            _Pragma("unroll")                                                 \
            for (int j4 = 0; j4 < KK / 4; ++j4) {                             \
                float4 av = ash4[j4];                                         \
                v2f lo; lo.x = av.x; lo.y = av.y;                             \
                v2f hi; hi.x = av.z; hi.y = av.w;                             \
                if (j4 & 1) {                                                 \
                    a2 = fma2(lo, acl[2 * j4], a2);                           \
                    a3 = fma2(hi, acl[2 * j4 + 1], a3);                       \
                } else {                                                      \
                    a0 = fma2(lo, acl[2 * j4], a0);                           \
                    a1 = fma2(hi, acl[2 * j4 + 1], a1);                       \
                }                                                             \
            }                                                                 \
            v2f sv = (a0 + a1) + (a2 + a3);                                   \
            a = pc * (sv.x + sv.y);                                           \
        }                                                                     \
        if ((t & 3) == 3) {              /* Ii==3 or Ii==7 (t0 % 8 == 0) */   \
            float den = wave_reduce_sum(a);                                   \
            logd += (t >= emit_from) ? __logf(den) : 0.0f;                    \
            a *= __builtin_amdgcn_rcpf(den);                                  \
        }                                                                     \
        alpha_sh[k] = a;                                                      \
        __builtin_amdgcn_wave_barrier(); /* order LDS write vs next reads */  \
    }

    for (int mblk = 0; mblk < nsteps / 8; ++mblk) {
        FUSED_STEP(xA, xB, 0)
        FUSED_STEP(xB, xA, 1)
        FUSED_STEP(xA, xB, 2)
        FUSED_STEP(xB, xA, 3)
        FUSED_STEP(xA, xB, 4)
        FUSED_STEP(xB, xA, 5)
        FUSED_STEP(xA, xB, 6)
        FUSED_STEP(xB, xA, 7)
    }
#undef FUSED_STEP

    if (seg == NSEG - 1) out_alpha[(size_t)s * KK + k] = a;  // t=1023 normalized
    if (k == 0) seq_logd[seg * SS + s] = logd + macc;
}

// ---------------------------------------------------------------------------
// nll = -( sum seq_logd )   (log den'' and max-shift sums already combined)
__global__ __launch_bounds__(256) void finalize(
    const float* __restrict__ seq_logd, float* __restrict__ out_nll)
{
    float v = 0.0f;
    for (int j = threadIdx.x; j < NSEG * SS; j += 256) v += seq_logd[j];
#pragma unroll
    for (int off = 32; off > 0; off >>= 1)
        v += __shfl_xor(v, off, 64);
    __shared__ float sh[4];
    if ((threadIdx.x & 63) == 0) sh[threadIdx.x >> 6] = v;
    __syncthreads();
    if (threadIdx.x == 0) {
        double total = ((double)sh[0] + sh[1]) + ((double)sh[2] + sh[3]);
        out_nll[0] = (float)(-total);
    }
}

extern "C" void kernel_launch(void* const* d_in, const int* in_sizes, int n_in,
                              void* d_out, int out_size, void* d_ws, size_t ws_size,
                              hipStream_t stream) {
    const float* data    = (const float*)d_in[0];  // [T,S,D]
    const float* initial = (const float*)d_in[1];  // [K]
    const float* trans   = (const float*)d_in[2];  // [K,K]
    const float* means   = (const float*)d_in[3];  // [K,D]
    const float* covars  = (const float*)d_in[4];  // [K,D]

    float* out_alpha = (float*)d_out;                    // [S,K]
    float* out_nll   = (float*)d_out + (size_t)SS * KK;  // 1 float

    float* seq_logd = (float*)d_ws;                      // [NSEG*S]

    hmm_fused<<<dim3(SS, NSEG), 64, 0, stream>>>(
        data, initial, trans, means, covars, out_alpha, seq_logd);
    finalize<<<1, 256, 0, stream>>>(seq_logd, out_nll);
}

// Round 6
// 301.309 us; speedup vs baseline: 3.0186x; 1.0034x over previous
//
#include <hip/hip_runtime.h>
#include <hip/hip_fp16.h>
#include <math.h>

// T=1024 time steps, S=512 sequences, D=32 features, K=64 states (= wave width)
#define TT 1024
#define SS 512
#define DD 32
#define KK 64

#define LOG2PI_F 1.8378770664093453f

// Segmented forward recursion: NSEG segments of TT/NSEG emitted steps each;
// seg>0 burns in BURN steps from a flat init (contraction of the normalized
// recursion kills the init error; rounds 3-5 measured it below noise).
#define NSEG 4
#define SEGLEN (TT / NSEG)   // 256
#define BURN 64

// Workspace layout (d_ws): float seq_logd[NSEG*S] only.

typedef float v2f __attribute__((ext_vector_type(2)));

__device__ __forceinline__ v2f fma2(v2f a, v2f b, v2f c) {
#if __has_builtin(__builtin_elementwise_fma)
    return __builtin_elementwise_fma(a, b, c);
#else
    v2f r; r.x = fmaf(a.x, b.x, c.x); r.y = fmaf(a.y, b.y, c.y); return r;
#endif
}

// Zero-cost register pin: makes the value opaque (not rematerializable by
// re-loading from memory). Round-5 post-mortem: VGPR_Count=88 with a ~200-reg
// working set and zero scratch traffic => the compiler re-loaded acl/w2/m2
// from L1/L2 inside EVERY fused step (LICM refused to hoist ~40 wide loads
// out of the 8x-unrolled body), adding ~350 cy/step of issue+latency.
__device__ __forceinline__ void pin2(v2f& v) { asm volatile("" : "+v"(v)); }

// ---------------------------------------------------------------------------
// DPP wave64 reductions: 6 VALU-latency ops (~50 cy serial). Result broadcast
// via readlane.
template <int CTRL, int RMASK>
__device__ __forceinline__ float dpp_add(float x) {
    int t = __builtin_amdgcn_update_dpp(0, __float_as_int(x), CTRL, RMASK, 0xf, true);
    return x + __int_as_float(t);
}
template <int CTRL, int RMASK>
__device__ __forceinline__ float dpp_max(float x) {
    int xi = __float_as_int(x);
    int t = __builtin_amdgcn_update_dpp(xi, xi, CTRL, RMASK, 0xf, false);
    return fmaxf(x, __int_as_float(t));
}
__device__ __forceinline__ float wave_reduce_sum(float x) {
    x = dpp_add<0x111, 0xf>(x);   // row_shr:1
    x = dpp_add<0x112, 0xf>(x);   // row_shr:2
    x = dpp_add<0x114, 0xf>(x);   // row_shr:4
    x = dpp_add<0x118, 0xf>(x);   // row_shr:8
    x = dpp_add<0x142, 0xa>(x);   // row_bcast:15 into rows 1,3
    x = dpp_add<0x143, 0xc>(x);   // row_bcast:31 into rows 2,3 -> lane63 total
    return __int_as_float(__builtin_amdgcn_readlane(__float_as_int(x), 63));
}
__device__ __forceinline__ float wave_reduce_max(float x) {
    x = dpp_max<0x111, 0xf>(x);
    x = dpp_max<0x112, 0xf>(x);
    x = dpp_max<0x114, 0xf>(x);
    x = dpp_max<0x118, 0xf>(x);
    x = dpp_max<0x142, 0xa>(x);
    x = dpp_max<0x143, 0xc>(x);
    return __int_as_float(__builtin_amdgcn_readlane(__float_as_int(x), 63));
}

// ---------------------------------------------------------------------------
// Fused emission + forward recursion. One wave per (sequence, segment);
// lane = state k.
//  - x[t+1,s,:] (128 B wave-uniform) double-buffered one full step ahead.
//  - emission (48 pk-FMA + DPP-max + exp) depends only on data -> fills the
//    recursion chain's stall windows.
//  - DEFERRED NORMALIZATION (new): alpha_sh always holds raw (unnormalized)
//    a~; at (t&3)==3 the wave computes den = sum(a~) via DPP, log, rcp as
//    dangling (off-chain) work and folds the wave-uniform rcp(den) into the
//    NEXT step's pc (itself off-chain). The serial chain shrinks to:
//    publish -> ds_read_b128 x16 -> fma tree -> pc*sum -> publish.
//    Identical math modulo one benign reassociation (~1e-7 rel): a~ carries
//    the same magnitudes as the round-5 version at every step.
// amdgpu_waves_per_eu(1,2): min=1 is the setting that empirically yields
// generous allocation (rounds 2-4: 132 VGPRs, no remat); expect ~220 <= 256
// so runtime occupancy stays 2 waves/SIMD for the 2048-wave grid.
__global__ __launch_bounds__(64)
__attribute__((amdgpu_waves_per_eu(1, 2)))
void hmm_fused(
    const float* __restrict__ data,      // [T,S,D]
    const float* __restrict__ initial,   // [K]
    const float* __restrict__ trans,     // [K,K]
    const float* __restrict__ means,     // [K,D]
    const float* __restrict__ covars,    // [K,D]
    float* __restrict__ out_alpha,       // [S,K]
    float* __restrict__ seq_logd)        // [NSEG*S]
{
    const int s   = blockIdx.x;
    const int seg = blockIdx.y;
    const int k   = threadIdx.x;

    const int emit_from = seg * SEGLEN;
    const int t0        = seg ? (emit_from - BURN) : 0;
    const int nsteps    = seg ? (SEGLEN + BURN) : SEGLEN;

    // Per-lane (state-k) emission constants.
    v2f w2[DD / 2], m2[DD / 2];
    float c0 = DD * LOG2PI_F;
#pragma unroll
    for (int d = 0; d < DD; ++d) {
        float c = covars[k * DD + d];
        ((float*)w2)[d] = 1.0f / c;
        ((float*)m2)[d] = means[k * DD + d];
        c0 += __logf(c);
    }
#pragma unroll
    for (int j = 0; j < DD / 2; ++j) { pin2(w2[j]); pin2(m2[j]); }

    v2f acl[KK / 2];                     // pairs (A[2j][k], A[2j+1][k])
#pragma unroll
    for (int j = 0; j < KK / 2; ++j) {
        acl[j].x = trans[(2 * j) * KK + k];
        acl[j].y = trans[(2 * j + 1) * KK + k];
    }
#pragma unroll
    for (int j = 0; j < KK / 2; ++j) pin2(acl[j]);

    __shared__ __align__(16) float alpha_sh[KK];

    // x double-buffer: named arrays + compile-time selection.
    float4 xA[DD / 4], xB[DD / 4];
    {
        const float4* xp = (const float4*)(data + ((size_t)t0 * SS + s) * DD);
#pragma unroll
        for (int j = 0; j < DD / 4; ++j) xA[j] = xp[j];
    }

    const float init_k = seg ? 1.0f : initial[k];
    float logd = 0.0f;                   // sum(log den'') over emitted steps
    float macc = 0.0f;                   // sum(mx) over emitted steps
    float a = 0.0f;
    float scl = 1.0f;                    // pending rcp(den), wave-uniform

    // One fused step. CONSUME=(Ii&3)==0 folds the pending scale into pc;
    // PRODUCE=(Ii&3)==3 computes den/log/rcp off-chain from the register a.
#define FUSED_STEP(XCUR, XNXT, Ii)                                            \
    {                                                                         \
        const int t = t0 + 8 * mblk + (Ii);                                   \
        int tn = t + 1; if (tn >= TT) tn = TT - 1;       /* uniform clamp */  \
        const float4* xp =                                                    \
            (const float4*)(data + ((size_t)tn * SS + s) * DD);               \
        _Pragma("unroll")                                                     \
        for (int j = 0; j < DD / 4; ++j) XNXT[j] = xp[j];                     \
        /* emission (off-chain): q_k = sum_d w[k,d]*(x_d - m[k,d])^2 */       \
        v2f q0 = {0.0f, 0.0f}, q1 = {0.0f, 0.0f};                             \
        _Pragma("unroll")                                                     \
        for (int d4 = 0; d4 < DD / 4; ++d4) {                                 \
            float4 x = XCUR[d4];                                              \
            v2f xa; xa.x = x.x; xa.y = x.y;                                   \
            v2f xb; xb.x = x.z; xb.y = x.w;                                   \
            v2f ta = xa - m2[2 * d4];                                         \
            v2f tb = xb - m2[2 * d4 + 1];                                     \
            q0 = fma2(w2[2 * d4] * ta, ta, q0);                               \
            q1 = fma2(w2[2 * d4 + 1] * tb, tb, q1);                           \
        }                                                                     \
        float qq = (q0.x + q0.y) + (q1.x + q1.y);                             \
        float logp = -0.5f * (qq + c0);                                       \
        float mx = wave_reduce_max(logp);        /* DPP, wave-uniform */      \
        float pc = __expf(logp - mx);                                         \
        if (((Ii) & 3) == 0) pc *= scl;          /* fold pending rcp(den) */  \
        if (t >= emit_from) macc += mx;                                       \
        /* recursion: a~ = pc * (a~_prev . A[:,k])  (raw, unnormalized) */    \
        if ((Ii) == 0 && mblk == 0) {                                         \
            a = init_k * pc;                                                  \
        } else {                                                              \
            const float4* ash4 = (const float4*)alpha_sh;                     \
            v2f a0 = {0,0}, a1 = {0,0}, a2 = {0,0}, a3 = {0,0};               \
            _Pragma("unroll")                                                 \
            for (int j4 = 0; j4 < KK / 4; ++j4) {                             \
                float4 av = ash4[j4];                                         \
                v2f lo; lo.x = av.x; lo.y = av.y;                             \
                v2f hi; hi.x = av.z; hi.y = av.w;                             \
                if (j4 & 1) {                                                 \
                    a2 = fma2(lo, acl[2 * j4], a2);                           \
                    a3 = fma2(hi, acl[2 * j4 + 1], a3);                       \
                } else {                                                      \
                    a0 = fma2(lo, acl[2 * j4], a0);                           \
                    a1 = fma2(hi, acl[2 * j4 + 1], a1);                       \
                }                                                             \
            }                                                                 \
            v2f sv = (a0 + a1) + (a2 + a3);                                   \
            a = pc * (sv.x + sv.y);                                           \
        }                                                                     \
        alpha_sh[k] = a;                 /* publish raw BEFORE normalize */   \
        __builtin_amdgcn_wave_barrier(); /* order LDS write vs next reads */  \
        if (((Ii) & 3) == 3) {           /* off-chain: dangling reduce */     \
            float den = wave_reduce_sum(a);                                   \
            logd += (t >= emit_from) ? __logf(den) : 0.0f;                    \
            scl = __builtin_amdgcn_rcpf(den);                                 \
        }                                                                     \
    }

    for (int mblk = 0; mblk < nsteps / 8; ++mblk) {
        FUSED_STEP(xA, xB, 0)
        FUSED_STEP(xB, xA, 1)
        FUSED_STEP(xA, xB, 2)
        FUSED_STEP(xB, xA, 3)
        FUSED_STEP(xA, xB, 4)
        FUSED_STEP(xB, xA, 5)
        FUSED_STEP(xA, xB, 6)
        FUSED_STEP(xB, xA, 7)
    }
#undef FUSED_STEP

    // Last step (t = 1023 for the last segment) was a PRODUCE step: a is raw,
    // scl = rcp(den_last). Apply the deferred normalization for the output.
    if (seg == NSEG - 1) out_alpha[(size_t)s * KK + k] = a * scl;
    if (k == 0) seq_logd[seg * SS + s] = logd + macc;
}

// ---------------------------------------------------------------------------
// nll = -( sum seq_logd )   (log den'' and max-shift sums already combined)
__global__ __launch_bounds__(256) void finalize(
    const float* __restrict__ seq_logd, float* __restrict__ out_nll)
{
    float v = 0.0f;
    for (int j = threadIdx.x; j < NSEG * SS; j += 256) v += seq_logd[j];
#pragma unroll
    for (int off = 32; off > 0; off >>= 1)
        v += __shfl_xor(v, off, 64);
    __shared__ float sh[4];
    if ((threadIdx.x & 63) == 0) sh[threadIdx.x >> 6] = v;
    __syncthreads();
    if (threadIdx.x == 0) {
        double total = ((double)sh[0] + sh[1]) + ((double)sh[2] + sh[3]);
        out_nll[0] = (float)(-total);
    }
}

extern "C" void kernel_launch(void* const* d_in, const int* in_sizes, int n_in,
                              void* d_out, int out_size, void* d_ws, size_t ws_size,
                              hipStream_t stream) {
    const float* data    = (const float*)d_in[0];  // [T,S,D]
    const float* initial = (const float*)d_in[1];  // [K]
    const float* trans   = (const float*)d_in[2];  // [K,K]
    const float* means   = (const float*)d_in[3];  // [K,D]
    const float* covars  = (const float*)d_in[4];  // [K,D]

    float* out_alpha = (float*)d_out;                    // [S,K]
    float* out_nll   = (float*)d_out + (size_t)SS * KK;  // 1 float

    float* seq_logd = (float*)d_ws;                      // [NSEG*S]

    hmm_fused<<<dim3(SS, NSEG), 64, 0, stream>>>(
        data, initial, trans, means, covars, out_alpha, seq_logd);
    finalize<<<1, 256, 0, stream>>>(seq_logd, out_nll);
}